// Round 11
// baseline (69.928 us; speedup 1.0000x reference)
//
#include <hip/hip_runtime.h>
#include <hip/hip_bf16.h>
#include <math.h>

#define DD 256      // feature dim
#define SS 1024     // seq len
#define BB 8        // batch
#define NN 128      // nodes
#define KC 64       // k-chunk for fallback scorer

typedef __attribute__((ext_vector_type(8))) short short8;
typedef __attribute__((ext_vector_type(4))) float f32x4;

__device__ __forceinline__ unsigned short f2bf(float x) {
    unsigned u = __builtin_bit_cast(unsigned, x);
    u += 0x7fffu + ((u >> 16) & 1u);          // round-to-nearest-even
    return (unsigned short)(u >> 16);
}
__device__ __forceinline__ float bf2f(unsigned short h) {
    return __builtin_bit_cast(float, (unsigned)h << 16);
}

// ============ Kernel 0a (r9 verbatim, PASSED): doc -> hi/lo split ============
__global__ __launch_bounds__(256) void split_doc_kernel(
    const float* __restrict__ doc,
    unsigned short* __restrict__ doc_hi, unsigned short* __restrict__ doc_lo)
{
    const int idx = blockIdx.x * 256 + threadIdx.x;
    const float4* in4 = reinterpret_cast<const float4*>(doc);
    ushort4* h4p = reinterpret_cast<ushort4*>(doc_hi);
    ushort4* l4p = reinterpret_cast<ushort4*>(doc_lo);
#pragma unroll
    for (int r = 0; r < 4; ++r) {
        const int i = idx + r * 131072;
        const float4 v = in4[i];
        ushort4 h, l;
        h.x = f2bf(v.x); l.x = f2bf(v.x - bf2f(h.x));
        h.y = f2bf(v.y); l.y = f2bf(v.y - bf2f(h.y));
        h.z = f2bf(v.z); l.z = f2bf(v.z - bf2f(h.z));
        h.w = f2bf(v.w); l.w = f2bf(v.w - bf2f(h.w));
        h4p[i] = h; l4p[i] = l;
    }
}

// ============ Kernel 0b (verified): W1 -> W1T hi/lo ============
__global__ __launch_bounds__(256) void split_w1t_kernel(
    const float* __restrict__ W1,
    unsigned short* __restrict__ w1t_hi, unsigned short* __restrict__ w1t_lo)
{
    __shared__ float tl[64][65];
    const int tid = threadIdx.x;
    const int k0 = (blockIdx.x >> 2) * 64, n0 = (blockIdx.x & 3) * 64;
#pragma unroll
    for (int i = 0; i < 16; ++i) {
        const int idx = i * 256 + tid;
        const int r = idx >> 6, c = idx & 63;
        tl[r][c] = W1[(size_t)(k0 + r) * DD + n0 + c];
    }
    __syncthreads();
#pragma unroll
    for (int i = 0; i < 16; ++i) {
        const int idx = i * 256 + tid;
        const int nl = idx >> 6, kl = idx & 63;
        const float v = tl[kl][nl];
        const unsigned short h = f2bf(v);
        const size_t o = (size_t)(n0 + nl) * DD + k0 + kl;
        w1t_hi[o] = h;
        w1t_lo[o] = f2bf(v - bf2f(h));
    }
}

// ===== Kernel 0c (split_w1t clone per batch): doc -> docT hi/lo, docT[b][d][s] =====
__global__ __launch_bounds__(256) void split_docT_kernel(
    const float* __restrict__ doc,
    unsigned short* __restrict__ docT_hi, unsigned short* __restrict__ docT_lo)
{
    __shared__ float tl[64][65];
    const int tid = threadIdx.x;
    const int blk = blockIdx.x;       // 512 = 8b x 16st x 4dt
    const int dt  = blk & 3;
    const int st  = (blk >> 2) & 15;
    const int b   = blk >> 6;
    const int s0  = st * 64, d0 = dt * 64;
#pragma unroll
    for (int i = 0; i < 16; ++i) {
        const int idx = i * 256 + tid;
        const int r = idx >> 6, c = idx & 63;
        tl[r][c] = doc[((size_t)b * SS + s0 + r) * DD + d0 + c];
    }
    __syncthreads();
#pragma unroll
    for (int i = 0; i < 16; ++i) {
        const int idx = i * 256 + tid;
        const int dl = idx >> 6, sl = idx & 63;
        const float v = tl[sl][dl];
        const unsigned short h = f2bf(v);
        const size_t o = ((size_t)b * DD + d0 + dl) * SS + s0 + sl;
        docT_hi[o] = h;
        docT_lo[o] = f2bf(v - bf2f(h));
    }
}

// ============ Kernel 1: scorer GEMM (pure MFMA). grid 1024, 4 blocks/CU ============
// Block = 32 tokens x 256 cols; wave owns 32 tok x 16 cols (2 M-tiles).
// Fragment pattern identical to r9-verified scorer_mfma.
__global__ __launch_bounds__(256) void scorer_gemm_kernel(
    const unsigned short* __restrict__ doc_hi, const unsigned short* __restrict__ doc_lo,
    const unsigned short* __restrict__ w1t_hi, const unsigned short* __restrict__ w1t_lo,
    float* __restrict__ hbuf)
{
    const int tid  = threadIdx.x;
    const int wave = tid >> 6, lane = tid & 63;
    const int l15  = lane & 15, kg = lane >> 4;
    const int t0 = (blockIdx.x >> 2) * 32;
    const int n0 = (blockIdx.x & 3) * 64 + wave * 16;

    const f32x4 z = {0.f, 0.f, 0.f, 0.f};
    f32x4 acc0 = z, acc1 = z;

    const size_t arow0 = (size_t)(t0 + l15) * DD;
    const size_t arow1 = (size_t)(t0 + 16 + l15) * DD;
    const size_t brow  = (size_t)(n0 + l15) * DD;

#pragma unroll
    for (int ks = 0; ks < 8; ++ks) {
        const int k = ks * 32 + kg * 8;
        const short8 a0h = *reinterpret_cast<const short8*>(doc_hi + arow0 + k);
        const short8 a0l = *reinterpret_cast<const short8*>(doc_lo + arow0 + k);
        const short8 a1h = *reinterpret_cast<const short8*>(doc_hi + arow1 + k);
        const short8 a1l = *reinterpret_cast<const short8*>(doc_lo + arow1 + k);
        const short8 bh  = *reinterpret_cast<const short8*>(w1t_hi + brow + k);
        const short8 bl  = *reinterpret_cast<const short8*>(w1t_lo + brow + k);
        acc0 = __builtin_amdgcn_mfma_f32_16x16x32_bf16(a0h, bh, acc0, 0, 0, 0);
        acc0 = __builtin_amdgcn_mfma_f32_16x16x32_bf16(a0h, bl, acc0, 0, 0, 0);
        acc0 = __builtin_amdgcn_mfma_f32_16x16x32_bf16(a0l, bh, acc0, 0, 0, 0);
        acc1 = __builtin_amdgcn_mfma_f32_16x16x32_bf16(a1h, bh, acc1, 0, 0, 0);
        acc1 = __builtin_amdgcn_mfma_f32_16x16x32_bf16(a1h, bl, acc1, 0, 0, 0);
        acc1 = __builtin_amdgcn_mfma_f32_16x16x32_bf16(a1l, bh, acc1, 0, 0, 0);
    }
    // C/D: col = lane&15 (B row), row = (lane>>4)*4 + reg (A row)  [m89-verified]
#pragma unroll
    for (int r = 0; r < 4; ++r) {
        hbuf[(size_t)(t0 + kg * 4 + r) * DD + n0 + l15]      = acc0[r];
        hbuf[(size_t)(t0 + 16 + kg * 4 + r) * DD + n0 + l15] = acc1[r];
    }
}

// ============ Kernel 2 (r9 verbatim, PASSED): combine = +b1, LN, GELU, @W2 ============
__global__ __launch_bounds__(256) void combine_kernel(
    const float* __restrict__ hbuf, const float* __restrict__ b1,
    const float* __restrict__ gamma, const float* __restrict__ beta,
    const float* __restrict__ W2, const float* __restrict__ b2,
    float* __restrict__ scores)
{
    const int tid  = threadIdx.x;
    const int wave = tid >> 6, lane = tid & 63;
    const int t0   = blockIdx.x * 16;
    const int c0   = lane * 4;

    const float4 bv  = *reinterpret_cast<const float4*>(b1 + c0);
    const float4 gm  = *reinterpret_cast<const float4*>(gamma + c0);
    const float4 be  = *reinterpret_cast<const float4*>(beta + c0);
    const float4 w2v = *reinterpret_cast<const float4*>(W2 + c0);
    const float  b2v = b2[0];

#pragma unroll
    for (int t = 0; t < 4; ++t) {
        const int row = t0 + wave * 4 + t;
        float4 h = *reinterpret_cast<const float4*>(hbuf + (size_t)row * DD + c0);
        h.x += bv.x; h.y += bv.y; h.z += bv.z; h.w += bv.w;

        float s1 = h.x + h.y + h.z + h.w;
        float s2 = h.x * h.x + h.y * h.y + h.z * h.z + h.w * h.w;
#pragma unroll
        for (int off = 32; off > 0; off >>= 1) {
            s1 += __shfl_xor(s1, off, 64);
            s2 += __shfl_xor(s2, off, 64);
        }
        const float mean = s1 * (1.f / DD);
        const float var  = s2 * (1.f / DD) - mean * mean;
        const float inv  = rsqrtf(var + 1e-5f);

        const float n0 = (h.x - mean) * inv * gm.x + be.x;
        const float n1 = (h.y - mean) * inv * gm.y + be.y;
        const float n2 = (h.z - mean) * inv * gm.z + be.z;
        const float n3 = (h.w - mean) * inv * gm.w + be.w;
        const float kq = 0.70710678118654752f;
        const float g0 = 0.5f * n0 * (1.f + erff(n0 * kq));
        const float g1 = 0.5f * n1 * (1.f + erff(n1 * kq));
        const float g2 = 0.5f * n2 * (1.f + erff(n2 * kq));
        const float g3 = 0.5f * n3 * (1.f + erff(n3 * kq));
        float sc = g0 * w2v.x + g1 * w2v.y + g2 * w2v.z + g3 * w2v.w;
#pragma unroll
        for (int off = 32; off > 0; off >>= 1) sc += __shfl_xor(sc, off, 64);
        if (lane == 0) scores[row] = sc + b2v;
    }
}

// ====== Kernel 3: masked softmax -> bf16 hi/lo weights ======
__global__ __launch_bounds__(256) void statsw_bf16_kernel(
    const float* __restrict__ mapping, const float* __restrict__ scores,
    unsigned short* __restrict__ w_hi, unsigned short* __restrict__ w_lo)
{
    __shared__ float sc_s[SS];
    const int tid  = threadIdx.x, lane = tid & 63;
    const int wave = __builtin_amdgcn_readfirstlane(tid >> 6);
    const int g0   = blockIdx.x * 4;
    const int b    = g0 >> 7;

    reinterpret_cast<float4*>(sc_s)[tid] =
        reinterpret_cast<const float4*>(scores + (size_t)b * SS)[tid];
    __syncthreads();

    const int g = g0 + wave;
    const float4* mrow4 = reinterpret_cast<const float4*>(mapping + (size_t)g * SS);
    const float4* sc4   = reinterpret_cast<const float4*>(sc_s);

    float4 mv[4], sv[4];
    float mx = -INFINITY;
#pragma unroll
    for (int q = 0; q < 4; ++q) {
        mv[q] = mrow4[lane + (q << 6)];
        sv[q] = sc4[lane + (q << 6)];
        if (mv[q].x > 0.5f) mx = fmaxf(mx, sv[q].x);
        if (mv[q].y > 0.5f) mx = fmaxf(mx, sv[q].y);
        if (mv[q].z > 0.5f) mx = fmaxf(mx, sv[q].z);
        if (mv[q].w > 0.5f) mx = fmaxf(mx, sv[q].w);
    }
#pragma unroll
    for (int off = 32; off > 0; off >>= 1) mx = fmaxf(mx, __shfl_xor(mx, off, 64));
    float z = 0.f;
    float4 ev[4];
#pragma unroll
    for (int q = 0; q < 4; ++q) {
        ev[q].x = (mv[q].x > 0.5f) ? __expf(sv[q].x - mx) : 0.f;
        ev[q].y = (mv[q].y > 0.5f) ? __expf(sv[q].y - mx) : 0.f;
        ev[q].z = (mv[q].z > 0.5f) ? __expf(sv[q].z - mx) : 0.f;
        ev[q].w = (mv[q].w > 0.5f) ? __expf(sv[q].w - mx) : 0.f;
        z += ev[q].x + ev[q].y + ev[q].z + ev[q].w;
    }
#pragma unroll
    for (int off = 32; off > 0; off >>= 1) z += __shfl_xor(z, off, 64);
    const float invz = (z > 0.f) ? (1.f / z) : 0.f;

    unsigned short* wh = w_hi + (size_t)g * SS;
    unsigned short* wl = w_lo + (size_t)g * SS;
#pragma unroll
    for (int q = 0; q < 4; ++q) {
        const float e0 = ev[q].x * invz, e1 = ev[q].y * invz;
        const float e2 = ev[q].z * invz, e3 = ev[q].w * invz;
        ushort4 h4, l4;
        h4.x = f2bf(e0); l4.x = f2bf(e0 - bf2f(h4.x));
        h4.y = f2bf(e1); l4.y = f2bf(e1 - bf2f(h4.y));
        h4.z = f2bf(e2); l4.z = f2bf(e2 - bf2f(h4.z));
        h4.w = f2bf(e3); l4.w = f2bf(e3 - bf2f(h4.w));
        const int s4 = lane + (q << 6);
        *reinterpret_cast<ushort4*>(wh + 4 * s4) = h4;
        *reinterpret_cast<ushort4*>(wl + 4 * s4) = l4;
    }
}

// ====== Kernel 4: pool GEMM out[n][d] = sum_s w[n][s] docT[d][s] (split-bf16 x3) ======
// grid 1024 = b(8) x nt(4: 32 nodes) x dt(4: 64 dims) x kc(8: 128 s).
// Wave owns 32n x 16d; structure identical to scorer_gemm.
__global__ __launch_bounds__(256) void pool_gemm_kernel(
    const unsigned short* __restrict__ w_hi, const unsigned short* __restrict__ w_lo,
    const unsigned short* __restrict__ docT_hi, const unsigned short* __restrict__ docT_lo,
    float* __restrict__ part)
{
    const int tid  = threadIdx.x;
    const int wave = tid >> 6, lane = tid & 63;
    const int l15  = lane & 15, kg = lane >> 4;
    const int blk = blockIdx.x;
    const int kc  = blk & 7;
    const int dt  = (blk >> 3) & 3;
    const int nt  = (blk >> 5) & 3;
    const int b   = blk >> 7;
    const int n0  = nt * 32;
    const int d0  = dt * 64 + wave * 16;
    const int k0  = kc * 128;

    const f32x4 z = {0.f, 0.f, 0.f, 0.f};
    f32x4 acc0 = z, acc1 = z;

    const size_t arow0 = ((size_t)(b * NN + n0 + l15)) * SS + k0;
    const size_t arow1 = ((size_t)(b * NN + n0 + 16 + l15)) * SS + k0;
    const size_t brow  = ((size_t)(b * DD + d0 + l15)) * SS + k0;

#pragma unroll
    for (int ks = 0; ks < 4; ++ks) {
        const int k = ks * 32 + kg * 8;
        const short8 a0h = *reinterpret_cast<const short8*>(w_hi + arow0 + k);
        const short8 a0l = *reinterpret_cast<const short8*>(w_lo + arow0 + k);
        const short8 a1h = *reinterpret_cast<const short8*>(w_hi + arow1 + k);
        const short8 a1l = *reinterpret_cast<const short8*>(w_lo + arow1 + k);
        const short8 bh  = *reinterpret_cast<const short8*>(docT_hi + brow + k);
        const short8 bl  = *reinterpret_cast<const short8*>(docT_lo + brow + k);
        acc0 = __builtin_amdgcn_mfma_f32_16x16x32_bf16(a0h, bh, acc0, 0, 0, 0);
        acc0 = __builtin_amdgcn_mfma_f32_16x16x32_bf16(a0h, bl, acc0, 0, 0, 0);
        acc0 = __builtin_amdgcn_mfma_f32_16x16x32_bf16(a0l, bh, acc0, 0, 0, 0);
        acc1 = __builtin_amdgcn_mfma_f32_16x16x32_bf16(a1h, bh, acc1, 0, 0, 0);
        acc1 = __builtin_amdgcn_mfma_f32_16x16x32_bf16(a1h, bl, acc1, 0, 0, 0);
        acc1 = __builtin_amdgcn_mfma_f32_16x16x32_bf16(a1l, bh, acc1, 0, 0, 0);
    }
    float* p = part + (size_t)kc * (BB * NN * DD);
#pragma unroll
    for (int r = 0; r < 4; ++r) {
        p[(size_t)(b * NN + n0 + kg * 4 + r) * DD + d0 + l15]      = acc0[r];
        p[(size_t)(b * NN + n0 + 16 + kg * 4 + r) * DD + d0 + l15] = acc1[r];
    }
}

// ---------------- Kernel 5: reduce 8 K-chunk partials ----------------
__global__ __launch_bounds__(256) void reduce_pool_kernel(
    const float* __restrict__ part, float* __restrict__ out)
{
    const int o = blockIdx.x * 256 + threadIdx.x;   // B*N*D = 262144
    float s = 0.f;
#pragma unroll
    for (int kc = 0; kc < 8; ++kc) s += part[(size_t)kc * (BB * NN * DD) + o];
    out[o] = s;
}

// ================= Fallback path (tiny ws): r5 verified kernels =================
__global__ __launch_bounds__(256) void scorer_kernel(
    const float* __restrict__ doc, const float* __restrict__ W1,
    const float* __restrict__ b1, const float* __restrict__ gamma,
    const float* __restrict__ beta, const float* __restrict__ W2,
    const float* __restrict__ b2, float* __restrict__ scores)
{
    __shared__ float xs[16][DD];
    __shared__ float w1s[KC][DD];

    const int tid  = threadIdx.x;
    const int wave = tid >> 6, lane = tid & 63;
    const int t0   = blockIdx.x * 16;
    const int c0   = lane * 4;

    {
        const float4* src = reinterpret_cast<const float4*>(doc + (size_t)t0 * DD);
        float4* dst = reinterpret_cast<float4*>(&xs[0][0]);
#pragma unroll
        for (int r = 0; r < 4; ++r) dst[tid + 256 * r] = src[tid + 256 * r];
    }

    float4 acc[4];
    {
        const float4 bv = *reinterpret_cast<const float4*>(b1 + c0);
#pragma unroll
        for (int t = 0; t < 4; ++t) acc[t] = bv;
    }
    const float* xw = &xs[wave * 4][0];

    for (int kc = 0; kc < DD / KC; ++kc) {
        __syncthreads();
        {
            const float4* wsrc = reinterpret_cast<const float4*>(W1 + (size_t)kc * KC * DD);
            float4* wdst = reinterpret_cast<float4*>(&w1s[0][0]);
#pragma unroll
            for (int r = 0; r < 16; ++r) wdst[tid + 256 * r] = wsrc[tid + 256 * r];
        }
        __syncthreads();
#pragma unroll 4
        for (int k4 = 0; k4 < KC / 4; ++k4) {
            const int kb = k4 * 4;
            const float4 w0 = *reinterpret_cast<const float4*>(&w1s[kb + 0][c0]);
            const float4 w1 = *reinterpret_cast<const float4*>(&w1s[kb + 1][c0]);
            const float4 w2 = *reinterpret_cast<const float4*>(&w1s[kb + 2][c0]);
            const float4 w3 = *reinterpret_cast<const float4*>(&w1s[kb + 3][c0]);
#pragma unroll
            for (int t = 0; t < 4; ++t) {
                const float4 xv = *reinterpret_cast<const float4*>(xw + (size_t)t * DD + kc * KC + kb);
                acc[t].x = fmaf(xv.x, w0.x, acc[t].x);
                acc[t].y = fmaf(xv.x, w0.y, acc[t].y);
                acc[t].z = fmaf(xv.x, w0.z, acc[t].z);
                acc[t].w = fmaf(xv.x, w0.w, acc[t].w);
                acc[t].x = fmaf(xv.y, w1.x, acc[t].x);
                acc[t].y = fmaf(xv.y, w1.y, acc[t].y);
                acc[t].z = fmaf(xv.y, w1.z, acc[t].z);
                acc[t].w = fmaf(xv.y, w1.w, acc[t].w);
                acc[t].x = fmaf(xv.z, w2.x, acc[t].x);
                acc[t].y = fmaf(xv.z, w2.y, acc[t].y);
                acc[t].z = fmaf(xv.z, w2.z, acc[t].z);
                acc[t].w = fmaf(xv.z, w2.w, acc[t].w);
                acc[t].x = fmaf(xv.w, w3.x, acc[t].x);
                acc[t].y = fmaf(xv.w, w3.y, acc[t].y);
                acc[t].z = fmaf(xv.w, w3.z, acc[t].z);
                acc[t].w = fmaf(xv.w, w3.w, acc[t].w);
            }
        }
    }

    const float4 gm = *reinterpret_cast<const float4*>(gamma + c0);
    const float4 be = *reinterpret_cast<const float4*>(beta + c0);
    const float4 w2v = *reinterpret_cast<const float4*>(W2 + c0);
    const float b2v = b2[0];

#pragma unroll
    for (int t = 0; t < 4; ++t) {
        float s1 = acc[t].x + acc[t].y + acc[t].z + acc[t].w;
        float s2 = acc[t].x * acc[t].x + acc[t].y * acc[t].y
                 + acc[t].z * acc[t].z + acc[t].w * acc[t].w;
#pragma unroll
        for (int off = 32; off > 0; off >>= 1) {
            s1 += __shfl_xor(s1, off, 64);
            s2 += __shfl_xor(s2, off, 64);
        }
        const float mean = s1 * (1.f / DD);
        const float var  = s2 * (1.f / DD) - mean * mean;
        const float inv  = rsqrtf(var + 1e-5f);
        float n0 = (acc[t].x - mean) * inv * gm.x + be.x;
        float n1 = (acc[t].y - mean) * inv * gm.y + be.y;
        float n2 = (acc[t].z - mean) * inv * gm.z + be.z;
        float n3 = (acc[t].w - mean) * inv * gm.w + be.w;
        const float kq = 0.70710678118654752f;
        float g0 = 0.5f * n0 * (1.f + erff(n0 * kq));
        float g1 = 0.5f * n1 * (1.f + erff(n1 * kq));
        float g2 = 0.5f * n2 * (1.f + erff(n2 * kq));
        float g3 = 0.5f * n3 * (1.f + erff(n3 * kq));
        float sc = g0 * w2v.x + g1 * w2v.y + g2 * w2v.z + g3 * w2v.w;
#pragma unroll
        for (int off = 32; off > 0; off >>= 1) sc += __shfl_xor(sc, off, 64);
        if (lane == 0) scores[t0 + wave * 4 + t] = sc + b2v;
    }
}

__global__ __launch_bounds__(256) void stats_kernel(
    const float* __restrict__ mapping, const float* __restrict__ scores,
    float* __restrict__ mx_out, float* __restrict__ invz_out)
{
    __shared__ float sc_s[SS];
    const int tid = threadIdx.x, wave = tid >> 6, lane = tid & 63;
    const int g0 = blockIdx.x * 4;
    const int b  = g0 >> 7;

    reinterpret_cast<float4*>(sc_s)[tid] =
        reinterpret_cast<const float4*>(scores + (size_t)b * SS)[tid];
    __syncthreads();

    const int g = g0 + wave;
    const float4* mrow4 = reinterpret_cast<const float4*>(mapping + (size_t)g * SS);
    const float4* sc4   = reinterpret_cast<const float4*>(sc_s);

    float4 mv[4], sv[4];
    float mx = -INFINITY;
#pragma unroll
    for (int q = 0; q < 4; ++q) {
        mv[q] = mrow4[lane + (q << 6)];
        sv[q] = sc4[lane + (q << 6)];
        if (mv[q].x > 0.5f) mx = fmaxf(mx, sv[q].x);
        if (mv[q].y > 0.5f) mx = fmaxf(mx, sv[q].y);
        if (mv[q].z > 0.5f) mx = fmaxf(mx, sv[q].z);
        if (mv[q].w > 0.5f) mx = fmaxf(mx, sv[q].w);
    }
#pragma unroll
    for (int off = 32; off > 0; off >>= 1) mx = fmaxf(mx, __shfl_xor(mx, off, 64));
    float z = 0.f;
#pragma unroll
    for (int q = 0; q < 4; ++q) {
        if (mv[q].x > 0.5f) z += __expf(sv[q].x - mx);
        if (mv[q].y > 0.5f) z += __expf(sv[q].y - mx);
        if (mv[q].z > 0.5f) z += __expf(sv[q].z - mx);
        if (mv[q].w > 0.5f) z += __expf(sv[q].w - mx);
    }
#pragma unroll
    for (int off = 32; off > 0; off >>= 1) z += __shfl_xor(z, off, 64);
    if (lane == 0) {
        mx_out[g]   = mx;
        invz_out[g] = (z > 0.f) ? (1.f / z) : 0.f;
    }
}

__global__ __launch_bounds__(256) void pool_direct_kernel(
    const float* __restrict__ doc, const float* __restrict__ mapping,
    const float* __restrict__ scores, const float* __restrict__ mx_in,
    const float* __restrict__ invz_in, float* __restrict__ out)
{
    __shared__ float w_lds[8][SS];

    const int bt    = blockIdx.x;
    const int ntile = bt & 15;
    const int b     = bt >> 4;
    const int tid = threadIdx.x, wave = tid >> 6, lane = tid & 63;

    {
        const int nl = wave * 2 + (lane >> 5);
        const int g  = b * NN + ntile * 8 + nl;
        const float mx   = mx_in[g];
        const float invz = invz_in[g];
        const float4* mrow4 = reinterpret_cast<const float4*>(mapping + (size_t)g * SS);
        const float4* srow4 = reinterpret_cast<const float4*>(scores + (size_t)b * SS);
        float4* wrow4 = reinterpret_cast<float4*>(&w_lds[nl][0]);
        const int idx0 = lane & 31;
#pragma unroll
        for (int q = 0; q < SS / 128; ++q) {
            const int idx = idx0 + 32 * q;
            const float4 mp = mrow4[idx];
            const float4 sv = srow4[idx];
            float4 e;
            e.x = (mp.x > 0.5f) ? __expf(sv.x - mx) * invz : 0.f;
            e.y = (mp.y > 0.5f) ? __expf(sv.y - mx) * invz : 0.f;
            e.z = (mp.z > 0.5f) ? __expf(sv.z - mx) * invz : 0.f;
            e.w = (mp.w > 0.5f) ? __expf(sv.w - mx) * invz : 0.f;
            wrow4[idx] = e;
        }
    }
    __syncthreads();

    float acc[8];
#pragma unroll
    for (int n = 0; n < 8; ++n) acc[n] = 0.f;
    const float* docb = doc + (size_t)b * SS * DD;

    for (int s4 = 0; s4 < SS; s4 += 4) {
        const float d0 = docb[(size_t)(s4 + 0) * DD + tid];
        const float d1 = docb[(size_t)(s4 + 1) * DD + tid];
        const float d2 = docb[(size_t)(s4 + 2) * DD + tid];
        const float d3 = docb[(size_t)(s4 + 3) * DD + tid];
#pragma unroll
        for (int n = 0; n < 8; ++n) {
            const float4 wv = *reinterpret_cast<const float4*>(&w_lds[n][s4]);
            acc[n] = fmaf(wv.x, d0, acc[n]);
            acc[n] = fmaf(wv.y, d1, acc[n]);
            acc[n] = fmaf(wv.z, d2, acc[n]);
            acc[n] = fmaf(wv.w, d3, acc[n]);
        }
    }

    float* outb = out + (((size_t)b * NN) + (size_t)ntile * 8) * DD;
#pragma unroll
    for (int n = 0; n < 8; ++n) outb[(size_t)n * DD + tid] = acc[n];
}

extern "C" void kernel_launch(void* const* d_in, const int* in_sizes, int n_in,
                              void* d_out, int out_size, void* d_ws, size_t ws_size,
                              hipStream_t stream) {
    const float* doc     = (const float*)d_in[0];  // (B,S,D)
    const float* mapping = (const float*)d_in[1];  // (B,N,S)
    // d_in[2] = nodes_len (unused)
    const float* W1    = (const float*)d_in[3];    // (D,D)
    const float* b1    = (const float*)d_in[4];    // (D)
    const float* gamma = (const float*)d_in[5];    // (D)
    const float* beta  = (const float*)d_in[6];    // (D)
    const float* W2    = (const float*)d_in[7];    // (D,1)
    const float* b2    = (const float*)d_in[8];    // (1)
    float* out = (float*)d_out;                    // (B,N,D)

    char* base = (char*)d_ws;
    size_t off = 0;
    float* scores = (float*)(base + off); off += (size_t)BB * SS * 4;                     // 32 KiB
    float* hbuf   = (float*)(base + off); off += (size_t)BB * SS * DD * 4;                // 8 MiB
    unsigned short* doc_hi  = (unsigned short*)(base + off); off += (size_t)BB * SS * DD * 2;  // 4 MiB
    unsigned short* doc_lo  = (unsigned short*)(base + off); off += (size_t)BB * SS * DD * 2;  // 4 MiB
    unsigned short* docT_hi = (unsigned short*)(base + off); off += (size_t)BB * SS * DD * 2;  // 4 MiB
    unsigned short* docT_lo = (unsigned short*)(base + off); off += (size_t)BB * SS * DD * 2;  // 4 MiB
    unsigned short* w1t_hi  = (unsigned short*)(base + off); off += (size_t)DD * DD * 2;       // 128 KiB
    unsigned short* w1t_lo  = (unsigned short*)(base + off); off += (size_t)DD * DD * 2;       // 128 KiB
    unsigned short* w_hi    = (unsigned short*)(base + off); off += (size_t)BB * NN * SS * 2;  // 2 MiB
    unsigned short* w_lo    = (unsigned short*)(base + off); off += (size_t)BB * NN * SS * 2;  // 2 MiB
    float* part   = (float*)(base + off); off += (size_t)8 * BB * NN * DD * 4;            // 8 MiB
    const size_t need = off;

    if (ws_size >= need) {
        split_doc_kernel<<<512, 256, 0, stream>>>(doc, doc_hi, doc_lo);
        split_w1t_kernel<<<16, 256, 0, stream>>>(W1, w1t_hi, w1t_lo);
        split_docT_kernel<<<512, 256, 0, stream>>>(doc, docT_hi, docT_lo);
        scorer_gemm_kernel<<<1024, 256, 0, stream>>>(doc_hi, doc_lo, w1t_hi, w1t_lo, hbuf);
        combine_kernel<<<512, 256, 0, stream>>>(hbuf, b1, gamma, beta, W2, b2, scores);
        statsw_bf16_kernel<<<256, 256, 0, stream>>>(mapping, scores, w_hi, w_lo);
        pool_gemm_kernel<<<1024, 256, 0, stream>>>(w_hi, w_lo, docT_hi, docT_lo, part);
        reduce_pool_kernel<<<(BB * NN * DD) / 256, 256, 0, stream>>>(part, out);
    } else {
        float* mx   = scores + BB * SS;
        float* invz = mx + BB * NN;
        scorer_kernel<<<BB * SS / 16, 256, 0, stream>>>(doc, W1, b1, gamma, beta, W2, b2, scores);
        stats_kernel<<<(BB * NN) / 4, 256, 0, stream>>>(mapping, scores, mx, invz);
        pool_direct_kernel<<<BB * 16, 256, 0, stream>>>(doc, mapping, scores, mx, invz, out);
    }
}

// Round 12
// 53.339 us; speedup vs baseline: 1.3110x; 1.3110x over previous
//
#include <hip/hip_runtime.h>
#include <hip/hip_bf16.h>
#include <math.h>

#define DD 256      // feature dim
#define SS 1024     // seq len
#define BB 8        // batch
#define NN 128      // nodes
#define TOK 16      // tokens per scorer block
#define KC 64       // k-chunk staged in LDS (scorer)
#define NT 8        // nodes per pool tile
#define SC 8        // S-chunks in pool
#define SCH (SS/SC) // 128

// ============ Kernel 1 (r5 verbatim, PASSED @58.6us): fused scorer ============
// h = x @ W1 + b1 ; LN(h) ; GELU(erf) ; score = h @ W2 + b2
// 4 waves/block; wave owns 4 tokens; thread owns 4 columns (c0=4*lane).
// W1 staged in LDS k-chunks of 64 (64 KiB); inner loop pure LDS + FMA.
__global__ __launch_bounds__(256) void scorer_kernel(
    const float* __restrict__ doc, const float* __restrict__ W1,
    const float* __restrict__ b1, const float* __restrict__ gamma,
    const float* __restrict__ beta, const float* __restrict__ W2,
    const float* __restrict__ b2, float* __restrict__ scores)
{
    __shared__ float xs[TOK][DD];    // 16 KiB input tile
    __shared__ float w1s[KC][DD];    // 64 KiB W1 k-chunk

    const int tid  = threadIdx.x;
    const int wave = tid >> 6, lane = tid & 63;
    const int t0   = blockIdx.x * TOK;
    const int c0   = lane * 4;

    {
        const float4* src = reinterpret_cast<const float4*>(doc + (size_t)t0 * DD);
        float4* dst = reinterpret_cast<float4*>(&xs[0][0]);
#pragma unroll
        for (int r = 0; r < 4; ++r) dst[tid + 256 * r] = src[tid + 256 * r];
    }

    float4 acc[4];
    {
        const float4 bv = *reinterpret_cast<const float4*>(b1 + c0);
#pragma unroll
        for (int t = 0; t < 4; ++t) acc[t] = bv;
    }
    const float* xw = &xs[wave * 4][0];

    for (int kc = 0; kc < DD / KC; ++kc) {
        __syncthreads();
        {
            const float4* wsrc = reinterpret_cast<const float4*>(W1 + (size_t)kc * KC * DD);
            float4* wdst = reinterpret_cast<float4*>(&w1s[0][0]);
#pragma unroll
            for (int r = 0; r < 16; ++r) wdst[tid + 256 * r] = wsrc[tid + 256 * r];
        }
        __syncthreads();
#pragma unroll 4
        for (int k4 = 0; k4 < KC / 4; ++k4) {
            const int kb = k4 * 4;
            const float4 w0 = *reinterpret_cast<const float4*>(&w1s[kb + 0][c0]);
            const float4 w1 = *reinterpret_cast<const float4*>(&w1s[kb + 1][c0]);
            const float4 w2 = *reinterpret_cast<const float4*>(&w1s[kb + 2][c0]);
            const float4 w3 = *reinterpret_cast<const float4*>(&w1s[kb + 3][c0]);
#pragma unroll
            for (int t = 0; t < 4; ++t) {
                const float4 xv = *reinterpret_cast<const float4*>(xw + (size_t)t * DD + kc * KC + kb);
                acc[t].x = fmaf(xv.x, w0.x, acc[t].x);
                acc[t].y = fmaf(xv.x, w0.y, acc[t].y);
                acc[t].z = fmaf(xv.x, w0.z, acc[t].z);
                acc[t].w = fmaf(xv.x, w0.w, acc[t].w);
                acc[t].x = fmaf(xv.y, w1.x, acc[t].x);
                acc[t].y = fmaf(xv.y, w1.y, acc[t].y);
                acc[t].z = fmaf(xv.y, w1.z, acc[t].z);
                acc[t].w = fmaf(xv.y, w1.w, acc[t].w);
                acc[t].x = fmaf(xv.z, w2.x, acc[t].x);
                acc[t].y = fmaf(xv.z, w2.y, acc[t].y);
                acc[t].z = fmaf(xv.z, w2.z, acc[t].z);
                acc[t].w = fmaf(xv.z, w2.w, acc[t].w);
                acc[t].x = fmaf(xv.w, w3.x, acc[t].x);
                acc[t].y = fmaf(xv.w, w3.y, acc[t].y);
                acc[t].z = fmaf(xv.w, w3.z, acc[t].z);
                acc[t].w = fmaf(xv.w, w3.w, acc[t].w);
            }
        }
    }

    const float4 gm = *reinterpret_cast<const float4*>(gamma + c0);
    const float4 be = *reinterpret_cast<const float4*>(beta + c0);
    const float4 w2v = *reinterpret_cast<const float4*>(W2 + c0);
    const float b2v = b2[0];

#pragma unroll
    for (int t = 0; t < 4; ++t) {
        float s1 = acc[t].x + acc[t].y + acc[t].z + acc[t].w;
        float s2 = acc[t].x * acc[t].x + acc[t].y * acc[t].y
                 + acc[t].z * acc[t].z + acc[t].w * acc[t].w;
#pragma unroll
        for (int off = 32; off > 0; off >>= 1) {
            s1 += __shfl_xor(s1, off, 64);
            s2 += __shfl_xor(s2, off, 64);
        }
        const float mean = s1 * (1.f / DD);
        const float var  = s2 * (1.f / DD) - mean * mean;
        const float inv  = rsqrtf(var + 1e-5f);
        float n0 = (acc[t].x - mean) * inv * gm.x + be.x;
        float n1 = (acc[t].y - mean) * inv * gm.y + be.y;
        float n2 = (acc[t].z - mean) * inv * gm.z + be.z;
        float n3 = (acc[t].w - mean) * inv * gm.w + be.w;
        const float kq = 0.70710678118654752f;
        float g0 = 0.5f * n0 * (1.f + erff(n0 * kq));
        float g1 = 0.5f * n1 * (1.f + erff(n1 * kq));
        float g2 = 0.5f * n2 * (1.f + erff(n2 * kq));
        float g3 = 0.5f * n3 * (1.f + erff(n3 * kq));
        float sc = g0 * w2v.x + g1 * w2v.y + g2 * w2v.z + g3 * w2v.w;
#pragma unroll
        for (int off = 32; off > 0; off >>= 1) sc += __shfl_xor(sc, off, 64);
        if (lane == 0) scores[t0 + wave * 4 + t] = sc + b2v;
    }
}

// ====== Kernel 2: pool with INLINE softmax-numerator (no stats kernel) ======
// No max-subtraction: |score| is LN-bounded (~<6), exp is safe in f32.
// Per chunk: num[n][d] = sum_s e*doc, zpart[n] = sum_s e  (e = mask ? exp(score) : 0)
// grid = BB*16*SC = 1024; derived from r6's verified pool<8>.
__global__ __launch_bounds__(256) void pool_e_kernel(
    const float* __restrict__ doc, const float* __restrict__ mapping,
    const float* __restrict__ scores, float* __restrict__ part,
    float* __restrict__ zpart)
{
    __shared__ float w_lds[NT][SCH];   // 4 KiB
    __shared__ float z_s[NT];

    const int blk   = blockIdx.x;
    const int c     = blk % SC;
    const int bt    = blk / SC;
    const int ntile = bt & 15;
    const int b     = bt >> 4;
    const int s0    = c * SCH;
    const int tid = threadIdx.x, wave = tid >> 6, lane = tid & 63;

    // phase A: e-weights for NT nodes over this chunk; half-wave per node
    {
        const int nl = wave * 2 + (lane >> 5);
        const int g  = b * NN + ntile * NT + nl;
        const float4 mp = reinterpret_cast<const float4*>(mapping + (size_t)g * SS + s0)[lane & 31];
        const float4 sv = reinterpret_cast<const float4*>(scores + (size_t)b * SS + s0)[lane & 31];
        float4 e;
        e.x = (mp.x > 0.5f) ? __expf(sv.x) : 0.f;
        e.y = (mp.y > 0.5f) ? __expf(sv.y) : 0.f;
        e.z = (mp.z > 0.5f) ? __expf(sv.z) : 0.f;
        e.w = (mp.w > 0.5f) ? __expf(sv.w) : 0.f;
        reinterpret_cast<float4*>(&w_lds[nl][0])[lane & 31] = e;
        float z = e.x + e.y + e.z + e.w;
#pragma unroll
        for (int off = 16; off > 0; off >>= 1) z += __shfl_xor(z, off, 64);  // within 32-lane half
        if ((lane & 31) == 0) z_s[nl] = z;
    }
    __syncthreads();

    // phase C (r6 verbatim structure): acc[n] += w[n][s] * doc[s][tid]
    float acc[NT];
#pragma unroll
    for (int n = 0; n < NT; ++n) acc[n] = 0.f;
    const float* docb = doc + ((size_t)b * SS + s0) * DD;

    float d0 = docb[(size_t)0 * DD + tid], d1 = docb[(size_t)1 * DD + tid];
    float d2 = docb[(size_t)2 * DD + tid], d3 = docb[(size_t)3 * DD + tid];
    for (int s4 = 0; s4 < SCH - 4; s4 += 4) {
        const float n0 = docb[(size_t)(s4 + 4) * DD + tid];
        const float n1 = docb[(size_t)(s4 + 5) * DD + tid];
        const float n2 = docb[(size_t)(s4 + 6) * DD + tid];
        const float n3 = docb[(size_t)(s4 + 7) * DD + tid];
#pragma unroll
        for (int n = 0; n < NT; ++n) {
            const float4 wv = *reinterpret_cast<const float4*>(&w_lds[n][s4]);
            acc[n] = fmaf(wv.x, d0, acc[n]);
            acc[n] = fmaf(wv.y, d1, acc[n]);
            acc[n] = fmaf(wv.z, d2, acc[n]);
            acc[n] = fmaf(wv.w, d3, acc[n]);
        }
        d0 = n0; d1 = n1; d2 = n2; d3 = n3;
    }
    {
        const int s4 = SCH - 4;
#pragma unroll
        for (int n = 0; n < NT; ++n) {
            const float4 wv = *reinterpret_cast<const float4*>(&w_lds[n][s4]);
            acc[n] = fmaf(wv.x, d0, acc[n]);
            acc[n] = fmaf(wv.y, d1, acc[n]);
            acc[n] = fmaf(wv.z, d2, acc[n]);
            acc[n] = fmaf(wv.w, d3, acc[n]);
        }
    }

    float* p = part + (size_t)blk * (NT * DD);
#pragma unroll
    for (int n = 0; n < NT; ++n) p[(size_t)n * DD + tid] = acc[n];
    if (tid < NT) zpart[(size_t)blk * NT + tid] = z_s[tid];
}

// ---------------- Kernel 3: reduce SC chunk-partials + divide by Z ----------------
__global__ __launch_bounds__(256) void reduce_div_kernel(
    const float* __restrict__ part, const float* __restrict__ zpart,
    float* __restrict__ out)
{
    const int o = blockIdx.x * 256 + threadIdx.x;   // B*N*D
    const int d = o & 255;
    const int g = o >> 8;          // b*128 + n
    const int b = g >> 7;
    const int n = g & 127;
    const int ntile = n >> 3, nl = n & 7;
    const int bp0 = (b * 16 + ntile) * SC;
    float s = 0.f, z = 0.f;
#pragma unroll
    for (int c = 0; c < SC; ++c) {
        const int bp = bp0 + c;
        s += part[(size_t)bp * (NT * DD) + (size_t)nl * DD + d];
        z += zpart[(size_t)bp * NT + nl];
    }
    out[o] = (z > 0.f) ? (s / z) : 0.f;
}

// ================= Fallback path (tiny ws): r5 verified kernels =================
__global__ __launch_bounds__(256) void stats_kernel(
    const float* __restrict__ mapping, const float* __restrict__ scores,
    float* __restrict__ mx_out, float* __restrict__ invz_out)
{
    __shared__ float sc_s[SS];
    const int tid = threadIdx.x, wave = tid >> 6, lane = tid & 63;
    const int g0 = blockIdx.x * 4;
    const int b  = g0 >> 7;

    reinterpret_cast<float4*>(sc_s)[tid] =
        reinterpret_cast<const float4*>(scores + (size_t)b * SS)[tid];
    __syncthreads();

    const int g = g0 + wave;
    const float4* mrow4 = reinterpret_cast<const float4*>(mapping + (size_t)g * SS);
    const float4* sc4   = reinterpret_cast<const float4*>(sc_s);

    float4 mv[4], sv[4];
    float mx = -INFINITY;
#pragma unroll
    for (int q = 0; q < 4; ++q) {
        mv[q] = mrow4[lane + (q << 6)];
        sv[q] = sc4[lane + (q << 6)];
        if (mv[q].x > 0.5f) mx = fmaxf(mx, sv[q].x);
        if (mv[q].y > 0.5f) mx = fmaxf(mx, sv[q].y);
        if (mv[q].z > 0.5f) mx = fmaxf(mx, sv[q].z);
        if (mv[q].w > 0.5f) mx = fmaxf(mx, sv[q].w);
    }
#pragma unroll
    for (int off = 32; off > 0; off >>= 1) mx = fmaxf(mx, __shfl_xor(mx, off, 64));
    float z = 0.f;
#pragma unroll
    for (int q = 0; q < 4; ++q) {
        if (mv[q].x > 0.5f) z += __expf(sv[q].x - mx);
        if (mv[q].y > 0.5f) z += __expf(sv[q].y - mx);
        if (mv[q].z > 0.5f) z += __expf(sv[q].z - mx);
        if (mv[q].w > 0.5f) z += __expf(sv[q].w - mx);
    }
#pragma unroll
    for (int off = 32; off > 0; off >>= 1) z += __shfl_xor(z, off, 64);
    if (lane == 0) {
        mx_out[g]   = mx;
        invz_out[g] = (z > 0.f) ? (1.f / z) : 0.f;
    }
}

__global__ __launch_bounds__(256) void pool_direct_kernel(
    const float* __restrict__ doc, const float* __restrict__ mapping,
    const float* __restrict__ scores, const float* __restrict__ mx_in,
    const float* __restrict__ invz_in, float* __restrict__ out)
{
    __shared__ float w_lds[8][SS];

    const int bt    = blockIdx.x;
    const int ntile = bt & 15;
    const int b     = bt >> 4;
    const int tid = threadIdx.x, wave = tid >> 6, lane = tid & 63;

    {
        const int nl = wave * 2 + (lane >> 5);
        const int g  = b * NN + ntile * 8 + nl;
        const float mx   = mx_in[g];
        const float invz = invz_in[g];
        const float4* mrow4 = reinterpret_cast<const float4*>(mapping + (size_t)g * SS);
        const float4* srow4 = reinterpret_cast<const float4*>(scores + (size_t)b * SS);
        float4* wrow4 = reinterpret_cast<float4*>(&w_lds[nl][0]);
        const int idx0 = lane & 31;
#pragma unroll
        for (int q = 0; q < SS / 128; ++q) {
            const int idx = idx0 + 32 * q;
            const float4 mp = mrow4[idx];
            const float4 sv = srow4[idx];
            float4 e;
            e.x = (mp.x > 0.5f) ? __expf(sv.x - mx) * invz : 0.f;
            e.y = (mp.y > 0.5f) ? __expf(sv.y - mx) * invz : 0.f;
            e.z = (mp.z > 0.5f) ? __expf(sv.z - mx) * invz : 0.f;
            e.w = (mp.w > 0.5f) ? __expf(sv.w - mx) * invz : 0.f;
            wrow4[idx] = e;
        }
    }
    __syncthreads();

    float acc[8];
#pragma unroll
    for (int n = 0; n < 8; ++n) acc[n] = 0.f;
    const float* docb = doc + (size_t)b * SS * DD;

    for (int s4 = 0; s4 < SS; s4 += 4) {
        const float d0 = docb[(size_t)(s4 + 0) * DD + tid];
        const float d1 = docb[(size_t)(s4 + 1) * DD + tid];
        const float d2 = docb[(size_t)(s4 + 2) * DD + tid];
        const float d3 = docb[(size_t)(s4 + 3) * DD + tid];
#pragma unroll
        for (int n = 0; n < 8; ++n) {
            const float4 wv = *reinterpret_cast<const float4*>(&w_lds[n][s4]);
            acc[n] = fmaf(wv.x, d0, acc[n]);
            acc[n] = fmaf(wv.y, d1, acc[n]);
            acc[n] = fmaf(wv.z, d2, acc[n]);
            acc[n] = fmaf(wv.w, d3, acc[n]);
        }
    }

    float* outb = out + (((size_t)b * NN) + (size_t)ntile * 8) * DD;
#pragma unroll
    for (int n = 0; n < 8; ++n) outb[(size_t)n * DD + tid] = acc[n];
}

extern "C" void kernel_launch(void* const* d_in, const int* in_sizes, int n_in,
                              void* d_out, int out_size, void* d_ws, size_t ws_size,
                              hipStream_t stream) {
    const float* doc     = (const float*)d_in[0];  // (B,S,D)
    const float* mapping = (const float*)d_in[1];  // (B,N,S)
    // d_in[2] = nodes_len (unused)
    const float* W1    = (const float*)d_in[3];    // (D,D)
    const float* b1    = (const float*)d_in[4];    // (D)
    const float* gamma = (const float*)d_in[5];    // (D)
    const float* beta  = (const float*)d_in[6];    // (D)
    const float* W2    = (const float*)d_in[7];    // (D,1)
    const float* b2    = (const float*)d_in[8];    // (1)
    float* out = (float*)d_out;                    // (B,N,D)

    char* base = (char*)d_ws;
    size_t off = 0;
    float* scores = (float*)(base + off); off += (size_t)BB * SS * 4;                  // 32 KiB
    float* part   = (float*)(base + off); off += (size_t)BB * 16 * SC * NT * DD * 4;   // 8 MiB
    float* zpart  = (float*)(base + off); off += (size_t)BB * 16 * SC * NT * 4;        // 32 KiB
    const size_t need = off;

    scorer_kernel<<<BB * SS / TOK, 256, 0, stream>>>(doc, W1, b1, gamma, beta, W2, b2, scores);

    if (ws_size >= need) {
        pool_e_kernel<<<BB * 16 * SC, 256, 0, stream>>>(doc, mapping, scores, part, zpart);
        reduce_div_kernel<<<(BB * NN * DD) / 256, 256, 0, stream>>>(part, zpart, out);
    } else {
        float* mx   = scores + BB * SS;
        float* invz = mx + BB * NN;
        stats_kernel<<<(BB * NN) / 4, 256, 0, stream>>>(mapping, scores, mx, invz);
        pool_direct_kernel<<<BB * 16, 256, 0, stream>>>(doc, mapping, scores, mx, invz, out);
    }
}

// Round 13
// 53.269 us; speedup vs baseline: 1.3127x; 1.0013x over previous
//
#include <hip/hip_runtime.h>
#include <hip/hip_bf16.h>
#include <math.h>

#define DD 256      // feature dim
#define SS 1024     // seq len
#define BB 8        // batch
#define NN 128      // nodes
#define TOK 16      // tokens per scorer block
#define KC 64       // k-chunk staged in LDS (scorer)
#define NT 8        // nodes per pool tile
#define SC 8        // S-chunks in pool
#define SCH (SS/SC) // 128

// ============ Kernel 1 (r5 verbatim, PASSED @58.6us): fused scorer ============
// h = x @ W1 + b1 ; LN(h) ; GELU(erf) ; score = h @ W2 + b2
// 4 waves/block; wave owns 4 tokens; thread owns 4 columns (c0=4*lane).
// W1 staged in LDS k-chunks of 64 (64 KiB); inner loop pure LDS + FMA.
__global__ __launch_bounds__(256) void scorer_kernel(
    const float* __restrict__ doc, const float* __restrict__ W1,
    const float* __restrict__ b1, const float* __restrict__ gamma,
    const float* __restrict__ beta, const float* __restrict__ W2,
    const float* __restrict__ b2, float* __restrict__ scores)
{
    __shared__ float xs[TOK][DD];    // 16 KiB input tile
    __shared__ float w1s[KC][DD];    // 64 KiB W1 k-chunk

    const int tid  = threadIdx.x;
    const int wave = tid >> 6, lane = tid & 63;
    const int t0   = blockIdx.x * TOK;
    const int c0   = lane * 4;

    {
        const float4* src = reinterpret_cast<const float4*>(doc + (size_t)t0 * DD);
        float4* dst = reinterpret_cast<float4*>(&xs[0][0]);
#pragma unroll
        for (int r = 0; r < 4; ++r) dst[tid + 256 * r] = src[tid + 256 * r];
    }

    float4 acc[4];
    {
        const float4 bv = *reinterpret_cast<const float4*>(b1 + c0);
#pragma unroll
        for (int t = 0; t < 4; ++t) acc[t] = bv;
    }
    const float* xw = &xs[wave * 4][0];

    for (int kc = 0; kc < DD / KC; ++kc) {
        __syncthreads();
        {
            const float4* wsrc = reinterpret_cast<const float4*>(W1 + (size_t)kc * KC * DD);
            float4* wdst = reinterpret_cast<float4*>(&w1s[0][0]);
#pragma unroll
            for (int r = 0; r < 16; ++r) wdst[tid + 256 * r] = wsrc[tid + 256 * r];
        }
        __syncthreads();
#pragma unroll 4
        for (int k4 = 0; k4 < KC / 4; ++k4) {
            const int kb = k4 * 4;
            const float4 w0 = *reinterpret_cast<const float4*>(&w1s[kb + 0][c0]);
            const float4 w1 = *reinterpret_cast<const float4*>(&w1s[kb + 1][c0]);
            const float4 w2 = *reinterpret_cast<const float4*>(&w1s[kb + 2][c0]);
            const float4 w3 = *reinterpret_cast<const float4*>(&w1s[kb + 3][c0]);
#pragma unroll
            for (int t = 0; t < 4; ++t) {
                const float4 xv = *reinterpret_cast<const float4*>(xw + (size_t)t * DD + kc * KC + kb);
                acc[t].x = fmaf(xv.x, w0.x, acc[t].x);
                acc[t].y = fmaf(xv.x, w0.y, acc[t].y);
                acc[t].z = fmaf(xv.x, w0.z, acc[t].z);
                acc[t].w = fmaf(xv.x, w0.w, acc[t].w);
                acc[t].x = fmaf(xv.y, w1.x, acc[t].x);
                acc[t].y = fmaf(xv.y, w1.y, acc[t].y);
                acc[t].z = fmaf(xv.y, w1.z, acc[t].z);
                acc[t].w = fmaf(xv.y, w1.w, acc[t].w);
                acc[t].x = fmaf(xv.z, w2.x, acc[t].x);
                acc[t].y = fmaf(xv.z, w2.y, acc[t].y);
                acc[t].z = fmaf(xv.z, w2.z, acc[t].z);
                acc[t].w = fmaf(xv.z, w2.w, acc[t].w);
                acc[t].x = fmaf(xv.w, w3.x, acc[t].x);
                acc[t].y = fmaf(xv.w, w3.y, acc[t].y);
                acc[t].z = fmaf(xv.w, w3.z, acc[t].z);
                acc[t].w = fmaf(xv.w, w3.w, acc[t].w);
            }
        }
    }

    const float4 gm = *reinterpret_cast<const float4*>(gamma + c0);
    const float4 be = *reinterpret_cast<const float4*>(beta + c0);
    const float4 w2v = *reinterpret_cast<const float4*>(W2 + c0);
    const float b2v = b2[0];

#pragma unroll
    for (int t = 0; t < 4; ++t) {
        float s1 = acc[t].x + acc[t].y + acc[t].z + acc[t].w;
        float s2 = acc[t].x * acc[t].x + acc[t].y * acc[t].y
                 + acc[t].z * acc[t].z + acc[t].w * acc[t].w;
#pragma unroll
        for (int off = 32; off > 0; off >>= 1) {
            s1 += __shfl_xor(s1, off, 64);
            s2 += __shfl_xor(s2, off, 64);
        }
        const float mean = s1 * (1.f / DD);
        const float var  = s2 * (1.f / DD) - mean * mean;
        const float inv  = rsqrtf(var + 1e-5f);
        float n0 = (acc[t].x - mean) * inv * gm.x + be.x;
        float n1 = (acc[t].y - mean) * inv * gm.y + be.y;
        float n2 = (acc[t].z - mean) * inv * gm.z + be.z;
        float n3 = (acc[t].w - mean) * inv * gm.w + be.w;
        const float kq = 0.70710678118654752f;
        float g0 = 0.5f * n0 * (1.f + erff(n0 * kq));
        float g1 = 0.5f * n1 * (1.f + erff(n1 * kq));
        float g2 = 0.5f * n2 * (1.f + erff(n2 * kq));
        float g3 = 0.5f * n3 * (1.f + erff(n3 * kq));
        float sc = g0 * w2v.x + g1 * w2v.y + g2 * w2v.z + g3 * w2v.w;
#pragma unroll
        for (int off = 32; off > 0; off >>= 1) sc += __shfl_xor(sc, off, 64);
        if (lane == 0) scores[t0 + wave * 4 + t] = sc + b2v;
    }
}

// ====== Kernel 2: pool with INLINE softmax-numerator (no stats kernel) ======
// No max-subtraction: |score| is LN-bounded (~<6), exp is safe in f32.
// Per chunk: num[n][d] = sum_s e*doc, zpart[n] = sum_s e  (e = mask ? exp(score) : 0)
// grid = BB*16*SC = 1024; derived from r6's verified pool<8>.
__global__ __launch_bounds__(256) void pool_e_kernel(
    const float* __restrict__ doc, const float* __restrict__ mapping,
    const float* __restrict__ scores, float* __restrict__ part,
    float* __restrict__ zpart)
{
    __shared__ float w_lds[NT][SCH];   // 4 KiB
    __shared__ float z_s[NT];

    const int blk   = blockIdx.x;
    const int c     = blk % SC;
    const int bt    = blk / SC;
    const int ntile = bt & 15;
    const int b     = bt >> 4;
    const int s0    = c * SCH;
    const int tid = threadIdx.x, wave = tid >> 6, lane = tid & 63;

    // phase A: e-weights for NT nodes over this chunk; half-wave per node
    {
        const int nl = wave * 2 + (lane >> 5);
        const int g  = b * NN + ntile * NT + nl;
        const float4 mp = reinterpret_cast<const float4*>(mapping + (size_t)g * SS + s0)[lane & 31];
        const float4 sv = reinterpret_cast<const float4*>(scores + (size_t)b * SS + s0)[lane & 31];
        float4 e;
        e.x = (mp.x > 0.5f) ? __expf(sv.x) : 0.f;
        e.y = (mp.y > 0.5f) ? __expf(sv.y) : 0.f;
        e.z = (mp.z > 0.5f) ? __expf(sv.z) : 0.f;
        e.w = (mp.w > 0.5f) ? __expf(sv.w) : 0.f;
        reinterpret_cast<float4*>(&w_lds[nl][0])[lane & 31] = e;
        float z = e.x + e.y + e.z + e.w;
#pragma unroll
        for (int off = 16; off > 0; off >>= 1) z += __shfl_xor(z, off, 64);  // within 32-lane half
        if ((lane & 31) == 0) z_s[nl] = z;
    }
    __syncthreads();

    // phase C (r6 verbatim structure): acc[n] += w[n][s] * doc[s][tid]
    float acc[NT];
#pragma unroll
    for (int n = 0; n < NT; ++n) acc[n] = 0.f;
    const float* docb = doc + ((size_t)b * SS + s0) * DD;

    float d0 = docb[(size_t)0 * DD + tid], d1 = docb[(size_t)1 * DD + tid];
    float d2 = docb[(size_t)2 * DD + tid], d3 = docb[(size_t)3 * DD + tid];
    for (int s4 = 0; s4 < SCH - 4; s4 += 4) {
        const float n0 = docb[(size_t)(s4 + 4) * DD + tid];
        const float n1 = docb[(size_t)(s4 + 5) * DD + tid];
        const float n2 = docb[(size_t)(s4 + 6) * DD + tid];
        const float n3 = docb[(size_t)(s4 + 7) * DD + tid];
#pragma unroll
        for (int n = 0; n < NT; ++n) {
            const float4 wv = *reinterpret_cast<const float4*>(&w_lds[n][s4]);
            acc[n] = fmaf(wv.x, d0, acc[n]);
            acc[n] = fmaf(wv.y, d1, acc[n]);
            acc[n] = fmaf(wv.z, d2, acc[n]);
            acc[n] = fmaf(wv.w, d3, acc[n]);
        }
        d0 = n0; d1 = n1; d2 = n2; d3 = n3;
    }
    {
        const int s4 = SCH - 4;
#pragma unroll
        for (int n = 0; n < NT; ++n) {
            const float4 wv = *reinterpret_cast<const float4*>(&w_lds[n][s4]);
            acc[n] = fmaf(wv.x, d0, acc[n]);
            acc[n] = fmaf(wv.y, d1, acc[n]);
            acc[n] = fmaf(wv.z, d2, acc[n]);
            acc[n] = fmaf(wv.w, d3, acc[n]);
        }
    }

    float* p = part + (size_t)blk * (NT * DD);
#pragma unroll
    for (int n = 0; n < NT; ++n) p[(size_t)n * DD + tid] = acc[n];
    if (tid < NT) zpart[(size_t)blk * NT + tid] = z_s[tid];
}

// ---------------- Kernel 3: reduce SC chunk-partials + divide by Z ----------------
__global__ __launch_bounds__(256) void reduce_div_kernel(
    const float* __restrict__ part, const float* __restrict__ zpart,
    float* __restrict__ out)
{
    const int o = blockIdx.x * 256 + threadIdx.x;   // B*N*D
    const int d = o & 255;
    const int g = o >> 8;          // b*128 + n
    const int b = g >> 7;
    const int n = g & 127;
    const int ntile = n >> 3, nl = n & 7;
    const int bp0 = (b * 16 + ntile) * SC;
    float s = 0.f, z = 0.f;
#pragma unroll
    for (int c = 0; c < SC; ++c) {
        const int bp = bp0 + c;
        s += part[(size_t)bp * (NT * DD) + (size_t)nl * DD + d];
        z += zpart[(size_t)bp * NT + nl];
    }
    out[o] = (z > 0.f) ? (s / z) : 0.f;
}

// ================= Fallback path (tiny ws): r5 verified kernels =================
__global__ __launch_bounds__(256) void stats_kernel(
    const float* __restrict__ mapping, const float* __restrict__ scores,
    float* __restrict__ mx_out, float* __restrict__ invz_out)
{
    __shared__ float sc_s[SS];
    const int tid = threadIdx.x, wave = tid >> 6, lane = tid & 63;
    const int g0 = blockIdx.x * 4;
    const int b  = g0 >> 7;

    reinterpret_cast<float4*>(sc_s)[tid] =
        reinterpret_cast<const float4*>(scores + (size_t)b * SS)[tid];
    __syncthreads();

    const int g = g0 + wave;
    const float4* mrow4 = reinterpret_cast<const float4*>(mapping + (size_t)g * SS);
    const float4* sc4   = reinterpret_cast<const float4*>(sc_s);

    float4 mv[4], sv[4];
    float mx = -INFINITY;
#pragma unroll
    for (int q = 0; q < 4; ++q) {
        mv[q] = mrow4[lane + (q << 6)];
        sv[q] = sc4[lane + (q << 6)];
        if (mv[q].x > 0.5f) mx = fmaxf(mx, sv[q].x);
        if (mv[q].y > 0.5f) mx = fmaxf(mx, sv[q].y);
        if (mv[q].z > 0.5f) mx = fmaxf(mx, sv[q].z);
        if (mv[q].w > 0.5f) mx = fmaxf(mx, sv[q].w);
    }
#pragma unroll
    for (int off = 32; off > 0; off >>= 1) mx = fmaxf(mx, __shfl_xor(mx, off, 64));
    float z = 0.f;
#pragma unroll
    for (int q = 0; q < 4; ++q) {
        if (mv[q].x > 0.5f) z += __expf(sv[q].x - mx);
        if (mv[q].y > 0.5f) z += __expf(sv[q].y - mx);
        if (mv[q].z > 0.5f) z += __expf(sv[q].z - mx);
        if (mv[q].w > 0.5f) z += __expf(sv[q].w - mx);
    }
#pragma unroll
    for (int off = 32; off > 0; off >>= 1) z += __shfl_xor(z, off, 64);
    if (lane == 0) {
        mx_out[g]   = mx;
        invz_out[g] = (z > 0.f) ? (1.f / z) : 0.f;
    }
}

__global__ __launch_bounds__(256) void pool_direct_kernel(
    const float* __restrict__ doc, const float* __restrict__ mapping,
    const float* __restrict__ scores, const float* __restrict__ mx_in,
    const float* __restrict__ invz_in, float* __restrict__ out)
{
    __shared__ float w_lds[8][SS];

    const int bt    = blockIdx.x;
    const int ntile = bt & 15;
    const int b     = bt >> 4;
    const int tid = threadIdx.x, wave = tid >> 6, lane = tid & 63;

    {
        const int nl = wave * 2 + (lane >> 5);
        const int g  = b * NN + ntile * 8 + nl;
        const float mx   = mx_in[g];
        const float invz = invz_in[g];
        const float4* mrow4 = reinterpret_cast<const float4*>(mapping + (size_t)g * SS);
        const float4* srow4 = reinterpret_cast<const float4*>(scores + (size_t)b * SS);
        float4* wrow4 = reinterpret_cast<float4*>(&w_lds[nl][0]);
        const int idx0 = lane & 31;
#pragma unroll
        for (int q = 0; q < SS / 128; ++q) {
            const int idx = idx0 + 32 * q;
            const float4 mp = mrow4[idx];
            const float4 sv = srow4[idx];
            float4 e;
            e.x = (mp.x > 0.5f) ? __expf(sv.x - mx) * invz : 0.f;
            e.y = (mp.y > 0.5f) ? __expf(sv.y - mx) * invz : 0.f;
            e.z = (mp.z > 0.5f) ? __expf(sv.z - mx) * invz : 0.f;
            e.w = (mp.w > 0.5f) ? __expf(sv.w - mx) * invz : 0.f;
            wrow4[idx] = e;
        }
    }
    __syncthreads();

    float acc[8];
#pragma unroll
    for (int n = 0; n < 8; ++n) acc[n] = 0.f;
    const float* docb = doc + (size_t)b * SS * DD;

    for (int s4 = 0; s4 < SS; s4 += 4) {
        const float d0 = docb[(size_t)(s4 + 0) * DD + tid];
        const float d1 = docb[(size_t)(s4 + 1) * DD + tid];
        const float d2 = docb[(size_t)(s4 + 2) * DD + tid];
        const float d3 = docb[(size_t)(s4 + 3) * DD + tid];
#pragma unroll
        for (int n = 0; n < 8; ++n) {
            const float4 wv = *reinterpret_cast<const float4*>(&w_lds[n][s4]);
            acc[n] = fmaf(wv.x, d0, acc[n]);
            acc[n] = fmaf(wv.y, d1, acc[n]);
            acc[n] = fmaf(wv.z, d2, acc[n]);
            acc[n] = fmaf(wv.w, d3, acc[n]);
        }
    }

    float* outb = out + (((size_t)b * NN) + (size_t)ntile * 8) * DD;
#pragma unroll
    for (int n = 0; n < 8; ++n) outb[(size_t)n * DD + tid] = acc[n];
}

extern "C" void kernel_launch(void* const* d_in, const int* in_sizes, int n_in,
                              void* d_out, int out_size, void* d_ws, size_t ws_size,
                              hipStream_t stream) {
    const float* doc     = (const float*)d_in[0];  // (B,S,D)
    const float* mapping = (const float*)d_in[1];  // (B,N,S)
    // d_in[2] = nodes_len (unused)
    const float* W1    = (const float*)d_in[3];    // (D,D)
    const float* b1    = (const float*)d_in[4];    // (D)
    const float* gamma = (const float*)d_in[5];    // (D)
    const float* beta  = (const float*)d_in[6];    // (D)
    const float* W2    = (const float*)d_in[7];    // (D,1)
    const float* b2    = (const float*)d_in[8];    // (1)
    float* out = (float*)d_out;                    // (B,N,D)

    char* base = (char*)d_ws;
    size_t off = 0;
    float* scores = (float*)(base + off); off += (size_t)BB * SS * 4;                  // 32 KiB
    float* part   = (float*)(base + off); off += (size_t)BB * 16 * SC * NT * DD * 4;   // 8 MiB
    float* zpart  = (float*)(base + off); off += (size_t)BB * 16 * SC * NT * 4;        // 32 KiB
    const size_t need = off;

    scorer_kernel<<<BB * SS / TOK, 256, 0, stream>>>(doc, W1, b1, gamma, beta, W2, b2, scores);

    if (ws_size >= need) {
        pool_e_kernel<<<BB * 16 * SC, 256, 0, stream>>>(doc, mapping, scores, part, zpart);
        reduce_div_kernel<<<(BB * NN * DD) / 256, 256, 0, stream>>>(part, zpart, out);
    } else {
        float* mx   = scores + BB * SS;
        float* invz = mx + BB * NN;
        stats_kernel<<<(BB * NN) / 4, 256, 0, stream>>>(mapping, scores, mx, invz);
        pool_direct_kernel<<<BB * 16, 256, 0, stream>>>(doc, mapping, scores, mx, invz, out);
    }
}